// Round 2
// baseline (730.733 us; speedup 1.0000x reference)
//
#include <hip/hip_runtime.h>

#define E 16
#define HID 32
#define NSTEP 10
#define TAU 0.5f
#define SIGMA 0.5f
#define RES 0.5f

typedef float v2 __attribute__((ext_vector_type(2)));

__device__ __forceinline__ v2 splat(float b) { v2 r; r.x = b; r.y = b; return r; }

// a*b + c, elementwise -> v_pk_fma_f32
__device__ __forceinline__ v2 pkfma(v2 a, float b, v2 c) {
    return __builtin_elementwise_fma(a, splat(b), c);
}
__device__ __forceinline__ v2 pkfma2(v2 a, v2 b, v2 c) {
    return __builtin_elementwise_fma(a, b, c);
}
__device__ __forceinline__ v2 pkrelu(v2 a) {
    return __builtin_elementwise_max(a, splat(0.0f));
}

__device__ __forceinline__ float fast_tanh(float v) {
    float e = __expf(2.0f * v);
    return 1.0f - __fdividef(2.0f, e + 1.0f);
}

__global__ __launch_bounds__(256, 2) void pdhg_kernel(
    const float* __restrict__ xg,  const float* __restrict__ Gg,  const float* __restrict__ hg,
    const float* __restrict__ W1,  const float* __restrict__ b1,
    const float* __restrict__ W2,  const float* __restrict__ b2,
    const float* __restrict__ Wmu, const float* __restrict__ bmu,
    const float* __restrict__ Wy,  const float* __restrict__ by,
    const float* __restrict__ Wp1, const float* __restrict__ bp1,
    const float* __restrict__ Wp2, const float* __restrict__ bp2,
    float* __restrict__ out, int npts)
{
    const int t = blockIdx.x * blockDim.x + threadIdx.x;
    const int p0 = 2 * t;
    if (p0 >= npts) return;

    // two points per thread, packed: lane = {pointA, pointB}
    const float4 xv = reinterpret_cast<const float4*>(xg)[t];
    v2 x0; x0.x = xv.x; x0.y = xv.z;
    v2 x1; x1.x = xv.y; x1.y = xv.w;

    // ---------------- encoder layer 1: relu(x @ W1 + b1) ----------------
    v2 f[HID];
    #pragma unroll
    for (int j = 0; j < HID; ++j) {
        f[j] = pkrelu(pkfma(x0, W1[j], pkfma(x1, W1[HID + j], splat(b1[j]))));
    }

    // ------- fused: layer2 -> (mu head, y head); g[j] never stored -------
    v2 mu[E];
    #pragma unroll
    for (int e = 0; e < E; ++e) mu[e] = splat(bmu[e]);
    v2 y0 = splat(by[0]), y1 = splat(by[1]);

    #pragma unroll
    for (int j = 0; j < HID; ++j) {
        v2 acc = splat(b2[j]);
        #pragma unroll
        for (int i = 0; i < HID; ++i) acc = pkfma(f[i], W2[i * HID + j], acc);
        acc = pkrelu(acc);
        #pragma unroll
        for (int e = 0; e < E; ++e) mu[e] = pkfma(acc, Wmu[j * E + e], mu[e]);
        y0 = pkfma(acc, Wy[j * 2], y0);
        y1 = pkfma(acc, Wy[j * 2 + 1], y1);
    }
    #pragma unroll
    for (int e = 0; e < E; ++e) mu[e] = pkrelu(mu[e]);
    y0.x = fast_tanh(y0.x); y0.y = fast_tanh(y0.y);
    y1.x = fast_tanh(y1.x); y1.y = fast_tanh(y1.y);

    // ---------------- a_row = x @ G^T - h^T ----------------
    v2 a[E];
    #pragma unroll
    for (int e = 0; e < E; ++e) {
        a[e] = pkfma(x0, Gg[e * 2], pkfma(x1, Gg[e * 2 + 1], splat(-hg[e])));
    }

    // ---------------- PDHG steps ----------------
    #pragma unroll 1
    for (int s = 0; s < NSTEP; ++s) {
        // y += SIGMA * (mu @ G); project to unit ball
        v2 v0 = splat(0.f), v1 = splat(0.f);
        #pragma unroll
        for (int e = 0; e < E; ++e) {
            v0 = pkfma(mu[e], Gg[e * 2], v0);
            v1 = pkfma(mu[e], Gg[e * 2 + 1], v1);
        }
        y0 = pkfma(v0, SIGMA, y0);
        y1 = pkfma(v1, SIGMA, y1);
        {
            const float na = sqrtf(fmaf(y0.x, y0.x, y1.x * y1.x));
            const float nb = sqrtf(fmaf(y0.y, y0.y, y1.y * y1.y));
            v2 sc; sc.x = __fdividef(1.0f, fmaxf(na, 1.0f));
                   sc.y = __fdividef(1.0f, fmaxf(nb, 1.0f));
            y0 *= sc; y1 *= sc;
        }

        // mu += TAU * (a - y @ G^T); z = mu @ G
        v2 z0 = splat(0.f), z1 = splat(0.f);
        #pragma unroll
        for (int e = 0; e < E; ++e) {
            v2 d = pkfma2(y0, splat(Gg[e * 2]), y1 * splat(Gg[e * 2 + 1]));
            mu[e] = pkfma(a[e] - d, TAU, mu[e]);
            z0 = pkfma(mu[e], Gg[e * 2], z0);
            z1 = pkfma(mu[e], Gg[e * 2 + 1], z1);
        }

        // fused prox head: h[k] produced and immediately consumed into delta
        v2 dl[E];
        #pragma unroll
        for (int e = 0; e < E; ++e) dl[e] = splat(bp2[e]);
        #pragma unroll
        for (int k = 0; k < HID; ++k) {
            v2 hk = pkrelu(pkfma(z0, Wp1[k], pkfma(z1, Wp1[HID + k], splat(bp1[k]))));
            #pragma unroll
            for (int e = 0; e < E; ++e) dl[e] = pkfma(hk, Wp2[k * E + e], dl[e]);
        }

        // mu = project_mu(mu + RES * dl)
        v2 p0v = splat(0.f), p1v = splat(0.f);
        #pragma unroll
        for (int e = 0; e < E; ++e) {
            mu[e] = pkrelu(pkfma(dl[e], RES, mu[e]));
            p0v = pkfma(mu[e], Gg[e * 2], p0v);
            p1v = pkfma(mu[e], Gg[e * 2 + 1], p1v);
        }
        {
            const float na = sqrtf(fmaf(p0v.x, p0v.x, p1v.x * p1v.x));
            const float nb = sqrtf(fmaf(p0v.y, p0v.y, p1v.y * p1v.y));
            v2 sc; sc.x = __fdividef(1.0f, fmaxf(na, 1.0f));
                   sc.y = __fdividef(1.0f, fmaxf(nb, 1.0f));
            #pragma unroll
            for (int e = 0; e < E; ++e) mu[e] *= sc;
        }
    }

    // ---------------- final project_mu ----------------
    {
        v2 p0v = splat(0.f), p1v = splat(0.f);
        #pragma unroll
        for (int e = 0; e < E; ++e) {
            mu[e] = pkrelu(mu[e]);
            p0v = pkfma(mu[e], Gg[e * 2], p0v);
            p1v = pkfma(mu[e], Gg[e * 2 + 1], p1v);
        }
        const float na = sqrtf(fmaf(p0v.x, p0v.x, p1v.x * p1v.x));
        const float nb = sqrtf(fmaf(p0v.y, p0v.y, p1v.y * p1v.y));
        v2 sc; sc.x = __fdividef(1.0f, fmaxf(na, 1.0f));
               sc.y = __fdividef(1.0f, fmaxf(nb, 1.0f));
        #pragma unroll
        for (int e = 0; e < E; ++e) mu[e] *= sc;
    }

    // ---------------- store: A = mu[].x (16 floats), B = mu[].y ----------------
    float4* outv = reinterpret_cast<float4*>(out + (size_t)p0 * E);
    outv[0] = make_float4(mu[0].x,  mu[1].x,  mu[2].x,  mu[3].x);
    outv[1] = make_float4(mu[4].x,  mu[5].x,  mu[6].x,  mu[7].x);
    outv[2] = make_float4(mu[8].x,  mu[9].x,  mu[10].x, mu[11].x);
    outv[3] = make_float4(mu[12].x, mu[13].x, mu[14].x, mu[15].x);
    outv[4] = make_float4(mu[0].y,  mu[1].y,  mu[2].y,  mu[3].y);
    outv[5] = make_float4(mu[4].y,  mu[5].y,  mu[6].y,  mu[7].y);
    outv[6] = make_float4(mu[8].y,  mu[9].y,  mu[10].y, mu[11].y);
    outv[7] = make_float4(mu[12].y, mu[13].y, mu[14].y, mu[15].y);
}

extern "C" void kernel_launch(void* const* d_in, const int* in_sizes, int n_in,
                              void* d_out, int out_size, void* d_ws, size_t ws_size,
                              hipStream_t stream) {
    const float* x   = (const float*)d_in[0];
    const float* G   = (const float*)d_in[1];
    const float* h   = (const float*)d_in[2];
    const float* W1  = (const float*)d_in[3];
    const float* b1  = (const float*)d_in[4];
    const float* W2  = (const float*)d_in[5];
    const float* b2  = (const float*)d_in[6];
    const float* Wmu = (const float*)d_in[7];
    const float* bmu = (const float*)d_in[8];
    const float* Wy  = (const float*)d_in[9];
    const float* by  = (const float*)d_in[10];
    const float* Wp1 = (const float*)d_in[11];
    const float* bp1 = (const float*)d_in[12];
    const float* Wp2 = (const float*)d_in[13];
    const float* bp2 = (const float*)d_in[14];

    const int npts = in_sizes[0] / 2;        // x is [N,2]
    const int nthreads = (npts + 1) / 2;     // 2 points per thread (packed v2)
    const int block = 256;
    const int grid = (nthreads + block - 1) / block;

    pdhg_kernel<<<grid, block, 0, stream>>>(x, G, h, W1, b1, W2, b2, Wmu, bmu,
                                            Wy, by, Wp1, bp1, Wp2, bp2,
                                            (float*)d_out, npts);
}

// Round 3
// 661.069 us; speedup vs baseline: 1.1054x; 1.1054x over previous
//
#include <hip/hip_runtime.h>

#define E 16
#define HID 32
#define NSTEP 10
#define TAU 0.5f
#define SIGMA 0.5f
#define RES 0.5f

typedef float v2 __attribute__((ext_vector_type(2)));

__device__ __forceinline__ v2 splat(float b) { v2 r; r.x = b; r.y = b; return r; }
__device__ __forceinline__ v2 vfma(v2 a, v2 b, v2 c) { return __builtin_elementwise_fma(a, b, c); }
__device__ __forceinline__ v2 vrelu(v2 a) { return __builtin_elementwise_max(a, splat(0.0f)); }
__device__ __forceinline__ v2 ld2(const float* __restrict__ p) {
    return *reinterpret_cast<const v2*>(p);
}
__device__ __forceinline__ float fast_tanh(float v) {
    float e = __expf(2.0f * v);
    return 1.0f - __fdividef(2.0f, e + 1.0f);
}
// scale = 1/max(sqrt(n2),1) == min(rsq(n2), 1)   (n2=0 -> rsq=inf -> min -> 1)
__device__ __forceinline__ float inv_norm_clamped(float n2) {
    return fminf(__builtin_amdgcn_rsqf(n2), 1.0f);
}

__global__ __launch_bounds__(256, 4) void pdhg_kernel(
    const float* __restrict__ xg,  const float* __restrict__ Gg,  const float* __restrict__ hg,
    const float* __restrict__ W1,  const float* __restrict__ b1,
    const float* __restrict__ W2,  const float* __restrict__ b2,
    const float* __restrict__ Wmu, const float* __restrict__ bmu,
    const float* __restrict__ Wy,  const float* __restrict__ by,
    const float* __restrict__ Wp1, const float* __restrict__ bp1,
    const float* __restrict__ Wp2, const float* __restrict__ bp2,
    float* __restrict__ out, int npts)
{
    const int t = blockIdx.x * blockDim.x + threadIdx.x;
    if (t >= npts) return;

    const float2 xv = reinterpret_cast<const float2*>(xg)[t];
    const float x0 = xv.x, x1 = xv.y;

    // ---------------- encoder layer 1 (j-packed pairs) ----------------
    v2 f[HID / 2];
    #pragma unroll
    for (int j2 = 0; j2 < HID / 2; ++j2) {
        v2 w0 = ld2(W1 + 2 * j2);          // W1[0][2j2..]
        v2 w1 = ld2(W1 + HID + 2 * j2);    // W1[1][2j2..]
        v2 bb = ld2(b1 + 2 * j2);
        f[j2] = vrelu(vfma(splat(x0), w0, vfma(splat(x1), w1, bb)));
    }

    // ------- fused layer2 -> (mu head, y head); g never stored -------
    v2 mu8[E / 2];
    #pragma unroll
    for (int e2 = 0; e2 < E / 2; ++e2) mu8[e2] = ld2(bmu + 2 * e2);
    v2 y = ld2(by);

    #pragma unroll
    for (int j2 = 0; j2 < HID / 2; ++j2) {
        v2 acc = ld2(b2 + 2 * j2);
        #pragma unroll
        for (int i = 0; i < HID; ++i) {
            const float fi = (i & 1) ? f[i >> 1].y : f[i >> 1].x;
            acc = vfma(splat(fi), ld2(W2 + i * HID + 2 * j2), acc);
        }
        acc = vrelu(acc);
        #pragma unroll
        for (int jj = 0; jj < 2; ++jj) {
            const int j = 2 * j2 + jj;
            const float gj = jj ? acc.y : acc.x;
            #pragma unroll
            for (int e2 = 0; e2 < E / 2; ++e2)
                mu8[e2] = vfma(splat(gj), ld2(Wmu + j * E + 2 * e2), mu8[e2]);
            y = vfma(splat(gj), ld2(Wy + j * 2), y);
        }
    }
    #pragma unroll
    for (int e2 = 0; e2 < E / 2; ++e2) mu8[e2] = vrelu(mu8[e2]);
    y.x = fast_tanh(y.x);
    y.y = fast_tanh(y.y);

    // ------- a = x@G^T - h ; c = a@G ; GtG = G^T G (2x2, runtime) -------
    v2 a8[E / 2];
    v2 cv = splat(0.0f);
    float g00 = 0.f, g01 = 0.f, g11 = 0.f;
    #pragma unroll
    for (int e = 0; e < E; ++e) {
        v2 gr = ld2(Gg + 2 * e);
        g00 = fmaf(gr.x, gr.x, g00);
        g01 = fmaf(gr.x, gr.y, g01);
        g11 = fmaf(gr.y, gr.y, g11);
        const float ae = fmaf(x0, gr.x, fmaf(x1, gr.y, -hg[e]));
        if (e & 1) a8[e >> 1].y = ae; else a8[e >> 1].x = ae;
        cv = vfma(splat(ae), gr, cv);
    }
    v2 gtg0; gtg0.x = g00; gtg0.y = g01;   // column 0/1 mix for y@(GtG)
    v2 gtg1; gtg1.x = g01; gtg1.y = g11;

    // ---------------- PDHG steps ----------------
    #pragma unroll 1
    for (int s = 0; s < NSTEP; ++s) {
        // v = mu@G  (dot over E with contiguous G rows)
        v2 v = splat(0.0f);
        #pragma unroll
        for (int e2 = 0; e2 < E / 2; ++e2) {
            v = vfma(splat(mu8[e2].x), ld2(Gg + 4 * e2), v);
            v = vfma(splat(mu8[e2].y), ld2(Gg + 4 * e2 + 2), v);
        }
        // y += SIGMA*v; project to unit ball
        y = vfma(splat(SIGMA), v, y);
        {
            const float n2 = fmaf(y.x, y.x, y.y * y.y);
            y *= splat(inv_norm_clamped(n2));
        }

        // z = v + TAU*(c - y@(GtG))   [== mu_new @ G without recomputing the dot]
        v2 ygg = vfma(splat(y.x), gtg0, splat(y.y) * gtg1);
        v2 z = vfma(splat(TAU), cv - ygg, v);

        // mu += TAU*(a - y@G^T)
        #pragma unroll
        for (int e2 = 0; e2 < E / 2; ++e2) {
            v2 t0 = y * ld2(Gg + 4 * e2);
            v2 t1 = y * ld2(Gg + 4 * e2 + 2);
            v2 d; d.x = t0.x + t0.y; d.y = t1.x + t1.y;
            mu8[e2] = vfma(splat(TAU), a8[e2] - d, mu8[e2]);
        }

        // fused prox head: hidden pair produced, immediately consumed into delta
        v2 dl[E / 2];
        #pragma unroll
        for (int e2 = 0; e2 < E / 2; ++e2) dl[e2] = ld2(bp2 + 2 * e2);
        #pragma unroll
        for (int j2 = 0; j2 < HID / 2; ++j2) {
            v2 w0 = ld2(Wp1 + 2 * j2);
            v2 w1 = ld2(Wp1 + HID + 2 * j2);
            v2 hb = ld2(bp1 + 2 * j2);
            v2 hk = vrelu(vfma(splat(z.x), w0, vfma(splat(z.y), w1, hb)));
            #pragma unroll
            for (int jj = 0; jj < 2; ++jj) {
                const float hv = jj ? hk.y : hk.x;
                const float* wrow = Wp2 + (2 * j2 + jj) * E;
                #pragma unroll
                for (int e2 = 0; e2 < E / 2; ++e2)
                    dl[e2] = vfma(splat(hv), ld2(wrow + 2 * e2), dl[e2]);
            }
        }

        // mu = project_mu(mu + RES*dl)
        v2 p = splat(0.0f);
        #pragma unroll
        for (int e2 = 0; e2 < E / 2; ++e2) {
            mu8[e2] = vrelu(vfma(splat(RES), dl[e2], mu8[e2]));
            p = vfma(splat(mu8[e2].x), ld2(Gg + 4 * e2), p);
            p = vfma(splat(mu8[e2].y), ld2(Gg + 4 * e2 + 2), p);
        }
        {
            const float n2 = fmaf(p.x, p.x, p.y * p.y);
            const v2 sc = splat(inv_norm_clamped(n2));
            #pragma unroll
            for (int e2 = 0; e2 < E / 2; ++e2) mu8[e2] *= sc;
        }
    }

    // ---------------- final project_mu (mu already >= 0) ----------------
    {
        v2 p = splat(0.0f);
        #pragma unroll
        for (int e2 = 0; e2 < E / 2; ++e2) {
            mu8[e2] = vrelu(mu8[e2]);
            p = vfma(splat(mu8[e2].x), ld2(Gg + 4 * e2), p);
            p = vfma(splat(mu8[e2].y), ld2(Gg + 4 * e2 + 2), p);
        }
        const float n2 = fmaf(p.x, p.x, p.y * p.y);
        const v2 sc = splat(inv_norm_clamped(n2));
        #pragma unroll
        for (int e2 = 0; e2 < E / 2; ++e2) mu8[e2] *= sc;
    }

    // ---------------- store 16 contiguous floats ----------------
    float4* outv = reinterpret_cast<float4*>(out + (size_t)t * E);
    outv[0] = make_float4(mu8[0].x, mu8[0].y, mu8[1].x, mu8[1].y);
    outv[1] = make_float4(mu8[2].x, mu8[2].y, mu8[3].x, mu8[3].y);
    outv[2] = make_float4(mu8[4].x, mu8[4].y, mu8[5].x, mu8[5].y);
    outv[3] = make_float4(mu8[6].x, mu8[6].y, mu8[7].x, mu8[7].y);
}

extern "C" void kernel_launch(void* const* d_in, const int* in_sizes, int n_in,
                              void* d_out, int out_size, void* d_ws, size_t ws_size,
                              hipStream_t stream) {
    const float* x   = (const float*)d_in[0];
    const float* G   = (const float*)d_in[1];
    const float* h   = (const float*)d_in[2];
    const float* W1  = (const float*)d_in[3];
    const float* b1  = (const float*)d_in[4];
    const float* W2  = (const float*)d_in[5];
    const float* b2  = (const float*)d_in[6];
    const float* Wmu = (const float*)d_in[7];
    const float* bmu = (const float*)d_in[8];
    const float* Wy  = (const float*)d_in[9];
    const float* by  = (const float*)d_in[10];
    const float* Wp1 = (const float*)d_in[11];
    const float* bp1 = (const float*)d_in[12];
    const float* Wp2 = (const float*)d_in[13];
    const float* bp2 = (const float*)d_in[14];

    const int npts = in_sizes[0] / 2;   // x is [N,2]
    const int block = 256;
    const int grid = (npts + block - 1) / block;

    pdhg_kernel<<<grid, block, 0, stream>>>(x, G, h, W1, b1, W2, b2, Wmu, bmu,
                                            Wy, by, Wp1, bp1, Wp2, bp2,
                                            (float*)d_out, npts);
}

// Round 4
// 566.359 us; speedup vs baseline: 1.2902x; 1.1672x over previous
//
#include <hip/hip_runtime.h>

#define E 16
#define HID 32
#define NSTEP 10
#define TAU 0.5f
#define SIGMA 0.5f
#define RES 0.5f

__device__ __forceinline__ float fast_tanh(float v) {
    float e = __expf(2.0f * v);
    return 1.0f - __fdividef(2.0f, e + 1.0f);
}
// scale = 1/max(sqrt(n2),1) == min(rsq(n2), 1)   (n2=0 -> rsq=inf -> min -> 1)
__device__ __forceinline__ float inv_norm_clamped(float n2) {
    return fminf(__builtin_amdgcn_rsqf(n2), 1.0f);
}

// waves_per_eu(4,4): pin scheduler target AND cap — 128-VGPR budget, no
// occupancy overshoot (R3: scheduler chased 8 waves/EU -> 64 VGPR -> 50MB spill)
__global__ __attribute__((amdgpu_waves_per_eu(4, 4))) __launch_bounds__(256)
void pdhg_kernel(
    const float* __restrict__ xg,  const float* __restrict__ Gg,  const float* __restrict__ hg,
    const float* __restrict__ W1,  const float* __restrict__ b1,
    const float* __restrict__ W2,  const float* __restrict__ b2,
    const float* __restrict__ Wmu, const float* __restrict__ bmu,
    const float* __restrict__ Wy,  const float* __restrict__ by,
    const float* __restrict__ Wp1, const float* __restrict__ bp1,
    const float* __restrict__ Wp2, const float* __restrict__ bp2,
    float* __restrict__ out, int npts)
{
    const int t = blockIdx.x * blockDim.x + threadIdx.x;
    if (t >= npts) return;

    const float2 xv = reinterpret_cast<const float2*>(xg)[t];
    const float x0 = xv.x, x1 = xv.y;

    // ---------------- encoder layer 1: relu(x @ W1 + b1) ----------------
    float f[HID];
    #pragma unroll
    for (int j = 0; j < HID; ++j)
        f[j] = fmaxf(fmaf(x0, W1[j], fmaf(x1, W1[HID + j], b1[j])), 0.0f);

    // ---------------- encoder layer 2 (row-major i-outer: contiguous s_loads) ----
    float g[HID];
    #pragma unroll
    for (int j = 0; j < HID; ++j) g[j] = b2[j];
    #pragma unroll
    for (int i = 0; i < HID; ++i) {
        const float fi = f[i];
        #pragma unroll
        for (int j = 0; j < HID; ++j) g[j] = fmaf(fi, W2[i * HID + j], g[j]);
    }
    #pragma unroll
    for (int j = 0; j < HID; ++j) g[j] = fmaxf(g[j], 0.0f);
    // f dead from here

    // ---------------- heads: mu = relu(g@Wmu+bmu), y = tanh(g@Wy+by) ----------
    float mu[E];
    #pragma unroll
    for (int e = 0; e < E; ++e) mu[e] = bmu[e];
    float y0 = by[0], y1 = by[1];
    #pragma unroll
    for (int j = 0; j < HID; ++j) {
        const float gj = g[j];
        #pragma unroll
        for (int e = 0; e < E; ++e) mu[e] = fmaf(gj, Wmu[j * E + e], mu[e]);
        y0 = fmaf(gj, Wy[j * 2], y0);
        y1 = fmaf(gj, Wy[j * 2 + 1], y1);
    }
    #pragma unroll
    for (int e = 0; e < E; ++e) mu[e] = fmaxf(mu[e], 0.0f);
    y0 = fast_tanh(y0);
    y1 = fast_tanh(y1);
    // g dead from here

    // ------- a = x@G^T - h ; c = a@G ; GtG (2x2) ; v = mu@G -------
    float a[E];
    float c0 = 0.f, c1 = 0.f, g00 = 0.f, g01 = 0.f, g11 = 0.f;
    float v0 = 0.f, v1 = 0.f;
    #pragma unroll
    for (int e = 0; e < E; ++e) {
        const float gx = Gg[2 * e], gy = Gg[2 * e + 1];
        g00 = fmaf(gx, gx, g00);
        g01 = fmaf(gx, gy, g01);
        g11 = fmaf(gy, gy, g11);
        const float ae = fmaf(x0, gx, fmaf(x1, gy, -hg[e]));
        a[e] = ae;
        c0 = fmaf(ae, gx, c0);
        c1 = fmaf(ae, gy, c1);
        v0 = fmaf(mu[e], gx, v0);
        v1 = fmaf(mu[e], gy, v1);
    }

    // ---------------- PDHG steps ----------------
    #pragma unroll 1
    for (int s = 0; s < NSTEP; ++s) {
        // y += SIGMA*v (v == mu@G maintained incrementally); unit-ball project
        y0 = fmaf(SIGMA, v0, y0);
        y1 = fmaf(SIGMA, v1, y1);
        {
            const float sc = inv_norm_clamped(fmaf(y0, y0, y1 * y1));
            y0 *= sc; y1 *= sc;
        }

        // z = mu'@G without the dot: z = v + TAU*(c - GtG@y)
        const float z0 = fmaf(TAU, c0 - fmaf(g00, y0, g01 * y1), v0);
        const float z1 = fmaf(TAU, c1 - fmaf(g01, y0, g11 * y1), v1);

        // mu += TAU*(a - y@G^T)
        #pragma unroll
        for (int e = 0; e < E; ++e) {
            const float d = fmaf(y0, Gg[2 * e], y1 * Gg[2 * e + 1]);
            mu[e] = fmaf(TAU, a[e] - d, mu[e]);
        }

        // fused prox head: hidden value produced & immediately consumed
        float dl[E];
        #pragma unroll
        for (int e = 0; e < E; ++e) dl[e] = bp2[e];
        #pragma unroll
        for (int k = 0; k < HID; ++k) {
            const float hk = fmaxf(fmaf(z0, Wp1[k], fmaf(z1, Wp1[HID + k], bp1[k])), 0.0f);
            #pragma unroll
            for (int e = 0; e < E; ++e) dl[e] = fmaf(hk, Wp2[k * E + e], dl[e]);
        }

        // mu = project_mu(mu + RES*dl); maintain v = sc * (pre-scale mu@G)
        float p0 = 0.f, p1 = 0.f;
        #pragma unroll
        for (int e = 0; e < E; ++e) {
            const float m = fmaxf(fmaf(RES, dl[e], mu[e]), 0.0f);
            mu[e] = m;
            p0 = fmaf(m, Gg[2 * e], p0);
            p1 = fmaf(m, Gg[2 * e + 1], p1);
        }
        const float sc = inv_norm_clamped(fmaf(p0, p0, p1 * p1));
        #pragma unroll
        for (int e = 0; e < E; ++e) mu[e] *= sc;
        v0 = sc * p0;
        v1 = sc * p1;
    }

    // final project_mu is the identity here: mu >= 0 and ||mu@G|| <= 1 already.

    // ---------------- store 16 contiguous floats ----------------
    float4* outv = reinterpret_cast<float4*>(out + (size_t)t * E);
    outv[0] = make_float4(mu[0],  mu[1],  mu[2],  mu[3]);
    outv[1] = make_float4(mu[4],  mu[5],  mu[6],  mu[7]);
    outv[2] = make_float4(mu[8],  mu[9],  mu[10], mu[11]);
    outv[3] = make_float4(mu[12], mu[13], mu[14], mu[15]);
}

extern "C" void kernel_launch(void* const* d_in, const int* in_sizes, int n_in,
                              void* d_out, int out_size, void* d_ws, size_t ws_size,
                              hipStream_t stream) {
    const float* x   = (const float*)d_in[0];
    const float* G   = (const float*)d_in[1];
    const float* h   = (const float*)d_in[2];
    const float* W1  = (const float*)d_in[3];
    const float* b1  = (const float*)d_in[4];
    const float* W2  = (const float*)d_in[5];
    const float* b2  = (const float*)d_in[6];
    const float* Wmu = (const float*)d_in[7];
    const float* bmu = (const float*)d_in[8];
    const float* Wy  = (const float*)d_in[9];
    const float* by  = (const float*)d_in[10];
    const float* Wp1 = (const float*)d_in[11];
    const float* bp1 = (const float*)d_in[12];
    const float* Wp2 = (const float*)d_in[13];
    const float* bp2 = (const float*)d_in[14];

    const int npts = in_sizes[0] / 2;   // x is [N,2]
    const int block = 256;
    const int grid = (npts + block - 1) / block;

    pdhg_kernel<<<grid, block, 0, stream>>>(x, G, h, W1, b1, W2, b2, Wmu, bmu,
                                            Wy, by, Wp1, bp1, Wp2, bp2,
                                            (float*)d_out, npts);
}